// Round 11
// baseline (93.024 us; speedup 1.0000x reference)
//
#include <hip/hip_runtime.h>

#define NA 150381
#define NC 90
#define PK 1024
#define CMAX 4096
#define MDET 100
#define STHR 0.996f
#define NTHR 0.5f
#define IMGF 896.0f
#define CPAD 32    // counts padded: one 128B cacheline per class
#define NBC 264    // per-class selection histogram bins (span>>8, padded)
#define NBF 1056   // final top-100 histogram bins (span>>6, padded)
#define SELT 192   // per-class selection target (>= MDET + suppression slack)

typedef unsigned long long u64;

__device__ __forceinline__ int binc(unsigned bits, unsigned SB) {
  int b = (int)((bits - SB) >> 8);
  return b < NBC - 1 ? b : NBC - 1;
}
__device__ __forceinline__ int binf(unsigned bits, unsigned SB) {
  int b = (int)((bits - SB) >> 6);
  return b < NBF - 1 ? b : NBF - 1;
}
// single source of truth for box decode -> bit-identical everywhere
__device__ __forceinline__ float4 decode_box(float4 a, float4 r) {
  float cxa = (a.x + a.z) * 0.5f, cya = (a.y + a.w) * 0.5f;
  float wa = a.z - a.x, ha = a.w - a.y;
  float w = expf(r.w) * wa, h = expf(r.z) * ha;
  float cy = r.x * ha + cya, cx = r.y * wa + cxa;
  float4 b;
  b.x = fminf(fmaxf(cx - w * 0.5f, 0.f), IMGF);
  b.y = fminf(fmaxf(cy - h * 0.5f, 0.f), IMGF);
  b.z = fminf(fmaxf(cx + w * 0.5f, 0.f), IMGF);
  b.w = fminf(fmaxf(cy + h * 0.5f, 0.f), IMGF);
  return b;
}

// ---------------- zero per-class counters + done counter ----------------
__global__ void k_zero(int* __restrict__ counts, int* __restrict__ done) {
  int i = blockIdx.x * blockDim.x + threadIdx.x;
  if (i < NC * CPAD) counts[i] = 0;
  if (i == 0) *done = 0;
}

// ---------------- threshold filter into per-class candidate lists ----------------
__global__ void k_collect(const float4* __restrict__ cls4, int* __restrict__ counts,
                          u64* __restrict__ cand) {
  const int total = NA * NC;
  const int nv4 = total >> 2;
  const int stride = gridDim.x * blockDim.x;
  for (int q = blockIdx.x * blockDim.x + threadIdx.x; q < nv4; q += stride) {
    float4 v4 = cls4[q];
    float vv[4] = {v4.x, v4.y, v4.z, v4.w};
    #pragma unroll
    for (int e = 0; e < 4; ++e) {
      float v = vv[e];
      if (v > STHR) {
        int f = q * 4 + e;
        int c = f % NC;
        int i = f / NC;
        int pos = atomicAdd(&counts[c * CPAD], 1);
        if (pos < CMAX)
          cand[(size_t)c * CMAX + pos] =
              ((u64)__float_as_uint(v) << 32) | (u64)(0xFFFFFFFFu - (unsigned)i);
      }
    }
  }
  int g = blockIdx.x * blockDim.x + threadIdx.x;
  if (g < total - nv4 * 4) {
    int f = nv4 * 4 + g;
    float v = ((const float*)cls4)[f];
    if (v > STHR) {
      int c = f % NC;
      int i = f / NC;
      int pos = atomicAdd(&counts[c * CPAD], 1);
      if (pos < CMAX)
        cand[(size_t)c * CMAX + pos] =
            ((u64)__float_as_uint(v) << 32) | (u64)(0xFFFFFFFFu - (unsigned)i);
    }
  }
}

__device__ __forceinline__ void bitonic_desc(u64* a, int n, int tid, int nth) {
  for (int k = 2; k <= n; k <<= 1) {
    for (int j = k >> 1; j > 0; j >>= 1) {
      __syncthreads();
      for (int i = tid; i < n; i += nth) {
        int ixj = i ^ j;
        if (ixj > i) {
          u64 x = a[i], y = a[ixj];
          if (((i & k) == 0) ? (x < y) : (x > y)) { a[i] = y; a[ixj] = x; }
        }
      }
    }
  }
  __syncthreads();
}

// ---------------- exact fallback for flagged classes (never taken normally) ------
__device__ void fb_class(int c, const int* counts, const u64* cand,
                         const float4* anc, const float4* reg,
                         u64* det, unsigned* aux, u64* lds) {
  const int tid = threadIdx.x;
  u64* sb = lds;                               // 4096 u64 = 32 KB
  float* fx1 = (float*)(lds + 4096);
  float* fy1 = fx1 + PK; float* fx2 = fy1 + PK; float* fy2 = fx2 + PK; float* fa = fy2 + PK;
  unsigned char* al = (unsigned char*)(fa + PK);
  const int M = min(counts[c * CPAD], CMAX);
  int NS = PK;
  while (NS < M) NS <<= 1;
  for (int t = tid; t < NS; t += 1024) sb[t] = (t < M) ? cand[(size_t)c * CMAX + t] : 0ULL;
  bitonic_desc(sb, NS, tid, 1024);
  const int Mk = min(M, PK);
  if (tid < Mk) {
    u64 k = sb[tid];
    unsigned aidx = 0xFFFFFFFFu - (unsigned)(k & 0xFFFFFFFFull);
    float4 b = decode_box(anc[aidx], reg[aidx]);
    fx1[tid] = b.x; fy1[tid] = b.y; fx2[tid] = b.z; fy2[tid] = b.w;
    fa[tid] = (b.z - b.x) * (b.w - b.y);
  }
  if (tid < PK) al[tid] = (tid < Mk) ? 1 : 0;
  __syncthreads();
  if (tid < 64) {                              // wave-serial greedy, O(M) per kept
    int kept = 0;
    for (int i = 0; i < Mk && kept < MDET; ++i) {
      if (!al[i]) continue;
      if (tid == 0) {
        u64 key = sb[i];
        int idx = c * MDET + kept;
        det[idx] = (key & 0xFFFFFFFF00000000ull) | (u64)(0xFFFFFFFFu - (unsigned)idx);
        aux[idx] = 0xFFFFFFFFu - (unsigned)(key & 0xFFFFFFFFull);
      }
      float x1 = fx1[i], y1 = fy1[i], x2 = fx2[i], y2 = fy2[i], ai = fa[i];
      for (int j = i + 1 + tid; j < Mk; j += 64) {
        float ix1 = fmaxf(x1, fx1[j]), iy1 = fmaxf(y1, fy1[j]);
        float ix2 = fminf(x2, fx2[j]), iy2 = fminf(y2, fy2[j]);
        float iw = fmaxf(ix2 - ix1, 0.f), ih = fmaxf(iy2 - iy1, 0.f);
        float inter = iw * ih;
        float uni = ai + fa[j] - inter;
        if (inter / fmaxf(uni, 1e-9f) > NTHR) al[j] = 0;
      }
      ++kept;
    }
  }
  __syncthreads();
}

// ---------------- fused: per-class select+sort+fixpoint-NMS, last block does top-100 --
// dyn layout: phase 1 uses it as cm2[1024][5] u64 (40 KB); final stage reuses it
// for fb scratch (53 KB) then hist(4.2 KB)+sel(8 KB). dyn = 56 KB.
__global__ __launch_bounds__(1024) void k_post(const int* __restrict__ counts,
                                               const u64* __restrict__ cand,
                                               const float4* __restrict__ anc,
                                               const float4* __restrict__ reg,
                                               const float* __restrict__ ta,
                                               const float* __restrict__ td,
                                               const float* __restrict__ rot,
                                               u64* __restrict__ det,
                                               unsigned* __restrict__ aux,
                                               int* __restrict__ flags,
                                               int* __restrict__ done,
                                               float* __restrict__ out) {
  extern __shared__ u64 dyn[];
  __shared__ u64 sel[256];
  __shared__ float sx1[256], sy1[256], sx2[256], sy2[256], sar[256];
  __shared__ u64 s_K[4];
  __shared__ int lhist[NBC];
  __shared__ int s_B, s_gc, s_cnt, s_last, s_any;
  __shared__ int wsum[16], wsuf[16];
  const int c = blockIdx.x, tid = threadIdx.x;
  const int wave = tid >> 6, lane = tid & 63;
  const unsigned SB = __float_as_uint(STHR);
  const int M = min(counts[c * CPAD], CMAX);

  if (tid < MDET) det[c * MDET + tid] = 0ULL;    // zero my det row first
  if (tid < 256) sel[tid] = 0ULL;
  if (tid == 0) { s_cnt = 0; }
  for (int t = tid; t < NBC; t += 1024) lhist[t] = 0;
  __syncthreads();

  // ---- selection histogram in LDS from the class cand list ----
  for (int t = tid; t < M; t += 1024) {
    u64 k = cand[(size_t)c * CMAX + t];
    atomicAdd(&lhist[binc((unsigned)(k >> 32), SB)], 1);
  }
  __syncthreads();

  // ---- threshold: suffix scan, 1 bin/thread ----
  {
    int s = (tid < NBC) ? lhist[tid] : 0;
    int ss = s;
    for (int d = 1; d < 64; d <<= 1) {
      int v = __shfl_down(ss, d);
      if (lane + d < 64) ss += v;
    }
    if (lane == 0) wsum[wave] = ss;
    __syncthreads();
    if (tid < 16) {
      int x = wsum[tid];
      for (int d = 1; d < 16; d <<= 1) {
        int v = __shfl_down(x, d);
        if (tid + d < 16) x += v;
      }
      wsuf[tid] = x;
    }
    __syncthreads();
    int suff = ss + ((wave < 15) ? wsuf[wave + 1] : 0);
    int suffn = suff - s;
    if (tid == 0 && wsuf[0] < SELT) { s_B = 0; s_gc = wsuf[0]; }
    if (suff >= SELT && suffn < SELT) { s_B = tid; s_gc = suff; }
    __syncthreads();
  }
  const int B = s_B;
  const int gc = s_gc;

  if (gc <= 256) {
    // ---- gather selected candidates ----
    for (int t = tid; t < M; t += 1024) {
      u64 k = cand[(size_t)c * CMAX + t];
      if (binc((unsigned)(k >> 32), SB) >= B) {
        int p = atomicAdd(&s_cnt, 1);
        if (p < 256) sel[p] = k;
      }
    }
    __syncthreads();

    // ---- sort 256 slots in ONE wave: 4 regs/lane, no barriers ----
    if (tid < 64 && gc > 0) {
      const int l = tid;
      u64 ea = sel[l], eb = sel[64 + l], ec = sel[128 + l], ed = sel[192 + l];
      auto CSWL = [&](u64& lo, u64& hi, int ilow, int k) {
        bool tml = ((ilow & k) == 0);
        u64 mx = lo >= hi ? lo : hi, mn = lo >= hi ? hi : lo;
        lo = tml ? mx : mn; hi = tml ? mn : mx;
      };
      auto SH = [&](u64& x, int ibase, int j, int k) {
        u64 p = __shfl_xor(x, j, 64);
        bool tm = ((((ibase | l) & k) == 0) != ((l & j) != 0));
        u64 mx = x >= p ? x : p, mn = x >= p ? p : x;
        x = tm ? mx : mn;
      };
      for (int k = 2; k <= 256; k <<= 1) {
        for (int j = k >> 1; j > 0; j >>= 1) {
          if (j == 128)      { CSWL(ea, ec, l, k);       CSWL(eb, ed, 64 | l, k); }
          else if (j == 64)  { CSWL(ea, eb, l, k);       CSWL(ec, ed, 128 | l, k); }
          else { SH(ea, 0, j, k); SH(eb, 64, j, k); SH(ec, 128, j, k); SH(ed, 192, j, k); }
        }
      }
      sel[l] = ea; sel[64 + l] = eb; sel[128 + l] = ec; sel[192 + l] = ed;
    }
    __syncthreads();

    // ---- stage decoded boxes for ranks [0, gc) ----
    u64 myk = 0; unsigned myaidx = 0;
    if (tid < 256 && tid < gc) {
      myk = sel[tid];
      myaidx = 0xFFFFFFFFu - (unsigned)(myk & 0xFFFFFFFFull);
      float4 b = decode_box(anc[myaidx], reg[myaidx]);
      sx1[tid] = b.x; sy1[tid] = b.y; sx2[tid] = b.z; sy2[tid] = b.w;
      sar[tid] = (b.z - b.x) * (b.w - b.y);
    }
    __syncthreads();

    // ---- colmask build: 4 threads per column ----
    {
      const int t = tid & 255, q = tid >> 8;
      u64 cw0 = 0, cw1 = 0, cw2 = 0, cw3 = 0;
      if (t < gc) {
        const float cx1 = sx1[t], cy1 = sy1[t], cx2 = sx2[t], cy2 = sy2[t], car = sar[t];
        for (int j = q; j < t; j += 4) {
          float ix1 = fmaxf(cx1, sx1[j]), iy1 = fmaxf(cy1, sy1[j]);
          float ix2 = fminf(cx2, sx2[j]), iy2 = fminf(cy2, sy2[j]);
          float iw = fmaxf(ix2 - ix1, 0.f), ih = fmaxf(iy2 - iy1, 0.f);
          float inter = iw * ih;
          float uni = car + sar[j] - inter;
          if (inter / fmaxf(uni, 1e-9f) > NTHR) {
            if (j < 64)       cw0 |= 1ULL << j;
            else if (j < 128) cw1 |= 1ULL << (j - 64);
            else if (j < 192) cw2 |= 1ULL << (j - 128);
            else              cw3 |= 1ULL << (j - 192);
          }
        }
      }
      dyn[tid * 5 + 0] = cw0; dyn[tid * 5 + 1] = cw1;
      dyn[tid * 5 + 2] = cw2; dyn[tid * 5 + 3] = cw3;
    }
    __syncthreads();
    if (tid < 512) {
      #pragma unroll
      for (int w = 0; w < 4; ++w) dyn[tid * 5 + w] |= dyn[(tid + 512) * 5 + w];
    }
    __syncthreads();
    if (tid < 256) {
      #pragma unroll
      for (int w = 0; w < 4; ++w) dyn[tid * 5 + w] |= dyn[(tid + 256) * 5 + w];
    }
    __syncthreads();

    // ---- ballot fixpoint in wave 0 (registers only, no barriers) ----
    if (tid < 64) {
      const int l = tid;
      u64 a00 = dyn[l*5+0],        a01 = dyn[l*5+1],        a02 = dyn[l*5+2],        a03 = dyn[l*5+3];
      u64 a10 = dyn[(64+l)*5+0],   a11 = dyn[(64+l)*5+1],   a12 = dyn[(64+l)*5+2],   a13 = dyn[(64+l)*5+3];
      u64 a20 = dyn[(128+l)*5+0],  a21 = dyn[(128+l)*5+1],  a22 = dyn[(128+l)*5+2],  a23 = dyn[(128+l)*5+3];
      u64 a30 = dyn[(192+l)*5+0],  a31 = dyn[(192+l)*5+1],  a32 = dyn[(192+l)*5+2],  a33 = dyn[(192+l)*5+3];
      u64 vm0 = (gc >= 64) ? ~0ULL : ((gc > 0) ? ((1ULL << gc) - 1) : 0ULL);
      u64 vm1 = (gc >= 128) ? ~0ULL : ((gc > 64) ? ((1ULL << (gc - 64)) - 1) : 0ULL);
      u64 vm2 = (gc >= 192) ? ~0ULL : ((gc > 128) ? ((1ULL << (gc - 128)) - 1) : 0ULL);
      u64 vm3 = (gc >= 256) ? ~0ULL : ((gc > 192) ? ((1ULL << (gc - 192)) - 1) : 0ULL);
      u64 K0 = vm0, K1 = vm1, K2 = vm2, K3 = vm3;
      for (int it = 0; it < 300; ++it) {
        bool al0 = ((a00 & K0) | (a01 & K1) | (a02 & K2) | (a03 & K3)) == 0ULL;
        bool al1 = ((a10 & K0) | (a11 & K1) | (a12 & K2) | (a13 & K3)) == 0ULL;
        bool al2 = ((a20 & K0) | (a21 & K1) | (a22 & K2) | (a23 & K3)) == 0ULL;
        bool al3 = ((a30 & K0) | (a31 & K1) | (a32 & K2) | (a33 & K3)) == 0ULL;
        u64 n0 = __ballot(al0) & vm0;
        u64 n1 = __ballot(al1) & vm1;
        u64 n2 = __ballot(al2) & vm2;
        u64 n3 = __ballot(al3) & vm3;
        bool same = (n0 == K0) && (n1 == K1) && (n2 == K2) && (n3 == K3);
        K0 = n0; K1 = n1; K2 = n2; K3 = n3;
        if (same) break;                          // fixpoint == greedy keep set
      }
      if (l == 0) { s_K[0] = K0; s_K[1] = K1; s_K[2] = K2; s_K[3] = K3; }
    }
    __syncthreads();

    // ---- slots via popcount; direct det/aux writes ----
    if (tid < 256 && tid < gc) {
      int g = tid >> 6;
      u64 kw = s_K[g];
      if ((kw >> (tid & 63)) & 1ULL) {
        int slot = __popcll(kw & ((1ULL << (tid & 63)) - 1ULL));
        for (int gg = 0; gg < g; ++gg) slot += __popcll(s_K[gg]);
        if (slot < MDET) {
          int idx = c * MDET + slot;
          det[idx] = (myk & 0xFFFFFFFF00000000ull) | (u64)(0xFFFFFFFFu - (unsigned)idx);
          aux[idx] = myaidx;
        }
      }
    }
    if (tid == 0) {
      int keptcnt = __popcll(s_K[0]) + __popcll(s_K[1]) + __popcll(s_K[2]) + __popcll(s_K[3]);
      flags[c] = (keptcnt < MDET && gc < min(M, PK)) ? 1 : 0;
    }
  } else {
    if (tid == 0) flags[c] = 1;                   // tie pileup: exact fallback
  }

  // ---- done-counter: last block runs the final top-100 stage ----
  __threadfence();                                // device-scope release
  __syncthreads();
  if (tid == 0) s_last = (atomicAdd(done, 1) == NC - 1);
  __syncthreads();
  if (!s_last) return;
  __threadfence();                                // acquire side

  // ---- fallback for flagged classes (exact, rarely taken) ----
  if (tid == 0) s_any = 0;
  __syncthreads();
  if (tid < NC && flags[tid] != 0) s_any = 1;
  __syncthreads();
  if (s_any) {
    for (int cc = 0; cc < NC; ++cc)
      if (flags[cc]) fb_class(cc, counts, cand, anc, reg, det, aux, dyn);
    __syncthreads();
  }

  // ---- global top-100: hist from global det reads -> select -> wave sort ----
  unsigned* fh = (unsigned*)dyn;                  // 1056 u32 (4.2 KB)
  u64* fsel = dyn + 640;                          // 1024 u64 at byte 5120
  __shared__ int s_fB, s_fgc, s_fcnt;
  for (int t = tid; t < NBF; t += 1024) fh[t] = 0u;
  if (tid < 1024) fsel[tid] = 0ULL;
  if (tid == 0) s_fcnt = 0;
  __syncthreads();

  const int NTOT = NC * MDET;
  for (int t = tid; t < NTOT; t += 1024) {
    u64 k = det[t];
    if (k) atomicAdd(&fh[binf((unsigned)(k >> 32), SB)], 1u);
  }
  __syncthreads();

  {
    const int b0 = 2 * tid;
    const unsigned h0 = (b0 < NBF) ? fh[b0] : 0u;
    const unsigned h1 = (b0 + 1 < NBF) ? fh[b0 + 1] : 0u;
    unsigned s = h0 + h1;
    unsigned ss = s;
    for (int d = 1; d < 64; d <<= 1) {
      unsigned v = __shfl_down(ss, d);
      if (lane + d < 64) ss += v;
    }
    if (lane == 0) wsum[wave] = (int)ss;
    __syncthreads();
    if (tid < 16) {
      int x = wsum[tid];
      for (int d = 1; d < 16; d <<= 1) {
        int v = __shfl_down(x, d);
        if (tid + d < 16) x += v;
      }
      wsuf[tid] = x;
    }
    __syncthreads();
    unsigned suff = ss + (unsigned)((wave < 15) ? wsuf[wave + 1] : 0);
    unsigned suffn = suff - s;
    if (tid == 0 && (unsigned)wsuf[0] < MDET) { s_fB = 0; s_fgc = wsuf[0]; }
    if (suff >= MDET && suffn < MDET) {
      if (suffn + h1 >= MDET) { s_fB = b0 + 1; s_fgc = (int)(suffn + h1); }
      else { s_fB = b0; s_fgc = (int)suff; }
    }
    __syncthreads();
  }
  const int fB = s_fB, fgc = s_fgc;

  for (int t = tid; t < NTOT; t += 1024) {
    u64 k = det[t];
    if (k && binf((unsigned)(k >> 32), SB) >= fB) {
      int p = atomicAdd(&s_fcnt, 1);
      if (p < 1024) fsel[p] = k;
    }
  }
  __syncthreads();

  if (fgc <= 128) {
    if (tid < 64) {
      u64 ea = fsel[lane], eb = fsel[64 + lane];
      auto CSWL = [&](u64& lo, u64& hi, int ilow, int k) {
        bool tml = ((ilow & k) == 0);
        u64 mx = lo >= hi ? lo : hi, mn = lo >= hi ? hi : lo;
        lo = tml ? mx : mn; hi = tml ? mn : mx;
      };
      auto SH = [&](u64& x, int ibase, int j, int k) {
        u64 p = __shfl_xor(x, j, 64);
        bool tm = ((((ibase | lane) & k) == 0) != ((lane & j) != 0));
        u64 mx = x >= p ? x : p, mn = x >= p ? p : x;
        x = tm ? mx : mn;
      };
      for (int k = 2; k <= 128; k <<= 1) {
        for (int j = k >> 1; j > 0; j >>= 1) {
          if (j == 64) CSWL(ea, eb, lane, k);
          else { SH(ea, 0, j, k); SH(eb, 64, j, k); }
        }
      }
      fsel[lane] = ea; fsel[64 + lane] = eb;
    }
    __syncthreads();
  } else {
    int NSf = 128;
    while (NSf < fgc && NSf < 1024) NSf <<= 1;
    bitonic_desc(fsel, NSf, tid, 1024);
  }

  // ---- gather top-100 outputs (decode on the fly) ----
  if (tid < MDET) {
    u64 key = fsel[tid];
    bool ok = (key != 0ULL);
    float b0 = -1.f, b1 = -1.f, b2 = -1.f, b3 = -1.f;
    float r0 = -1.f, r1 = -1.f, r2 = -1.f;
    float t0 = -1.f, t1 = -1.f, t2 = -1.f;
    float sc = -1.f, lab = -1.f;
    if (ok) {
      float score = __uint_as_float((unsigned)(key >> 32));
      unsigned idx = 0xFFFFFFFFu - (unsigned)(key & 0xFFFFFFFFull);
      int cc = idx / MDET;
      unsigned aidx = aux[idx];
      float4 bb = decode_box(anc[aidx], reg[aidx]);
      b0 = bb.x; b1 = bb.y; b2 = bb.z; b3 = bb.w;
      sc = score; lab = (float)cc;
      r0 = rot[aidx*3+0]; r1 = rot[aidx*3+1]; r2 = rot[aidx*3+2];
      float st = ta[aidx*3+2];
      t0 = ta[aidx*3+0] + td[aidx*3+0] * st;
      t1 = ta[aidx*3+1] + td[aidx*3+1] * st;
      t2 = td[aidx*3+2];
    }
    out[tid*4+0] = b0; out[tid*4+1] = b1; out[tid*4+2] = b2; out[tid*4+3] = b3;
    out[400 + tid] = sc;
    out[500 + tid] = lab;
    out[600 + tid*3+0] = r0; out[600 + tid*3+1] = r1; out[600 + tid*3+2] = r2;
    out[900 + tid*3+0] = t0; out[900 + tid*3+1] = t1; out[900 + tid*3+2] = t2;
  }
}

extern "C" void kernel_launch(void* const* d_in, const int* in_sizes, int n_in,
                              void* d_out, int out_size, void* d_ws, size_t ws_size,
                              hipStream_t stream) {
  const float* anchors        = (const float*)d_in[0];
  const float* regression     = (const float*)d_in[1];
  const float* classification = (const float*)d_in[2];
  const float* rotation       = (const float*)d_in[3];
  const float* tanch          = (const float*)d_in[4];
  const float* tdelta         = (const float*)d_in[5];
  float* out = (float*)d_out;

  char* ws = (char*)d_ws;
  size_t off = 0;
  auto alloc = [&](size_t bytes) -> void* {
    void* p = ws + off;
    off += (bytes + 255) & ~(size_t)255;
    return p;
  };
  int*      counts = (int*)alloc(NC * CPAD * 4);
  u64*      cand   = (u64*)alloc((size_t)NC * CMAX * 8);
  u64*      det    = (u64*)alloc((size_t)NC * MDET * 8);
  unsigned* aux    = (unsigned*)alloc((size_t)NC * MDET * 4);
  int*      flags  = (int*)alloc(NC * 4);
  int*      done   = (int*)alloc(4);

  k_zero<<<(NC * CPAD + 255) / 256, 256, 0, stream>>>(counts, done);
  k_collect<<<2048, 256, 0, stream>>>((const float4*)classification, counts, cand);

  hipFuncSetAttribute(reinterpret_cast<const void*>(k_post),
                      hipFuncAttributeMaxDynamicSharedMemorySize, 57344);
  k_post<<<NC, 1024, 57344, stream>>>(counts, cand,
                                      (const float4*)anchors, (const float4*)regression,
                                      tanch, tdelta, rotation,
                                      det, aux, flags, done, out);
}